// Round 1
// baseline (101.804 us; speedup 1.0000x reference)
//
#include <hip/hip_runtime.h>

#define BATCH 131072

typedef float v2f __attribute__((ext_vector_type(2)));

// ws layout (floats):
//  [0..35]     A': 6 folded decoder quadratic forms (6 coeffs each):
//              rec_k = (sum_i A'_k[i]*q[i])/(l^T l), q = (l0^2,l1^2,l2^2,l0l1,l0l2,l1l2)
//  [64..99]    enc RX coeffs: gate g=bb*6+w -> ws[64+2g]=cos(tx/2), ws[65+2g]=sin(tx/2)
//              EXCEPT block 2 (g>=12): ws[64+2g]=cos(tx), ws[65+2g]=2*sin(tx)
//              (block-2 gates are folded into the observable:
//               RX_k^dag Z_k RX_k = cos(tx) Z_k + sin(tx) Y_k; all other block-2
//               gates commute with Z_{0,1,2} and cancel)
//  [128..511]  enc diag per block bb: ws[128+128*bb+2r]=Re D_r, +1=Im D_r (bb=0,1 used)

__device__ __forceinline__ float fast_tanh(float v) {
    float e = __expf(2.0f * v);
    return 1.0f - 2.0f / (e + 1.0f);
}

template <int CTRL>
__device__ __forceinline__ float dppf(float v) {
    return __int_as_float(__builtin_amdgcn_update_dpp(
        0, __float_as_int(v), CTRL, 0xF, 0xF, true));
}
#define DPP_XOR1 0xB1  // quad_perm [1,0,3,2]
#define DPP_XOR2 0x4E  // quad_perm [2,3,0,1]

__device__ __forceinline__ v2f swap2(v2f v) { return __builtin_shufflevector(v, v, 1, 0); }

// ---------------------------------------------------------------------------
// prep
// ---------------------------------------------------------------------------
__global__ __launch_bounds__(256) void prep_kernel(const float* __restrict__ enc_w,
                                                   const float* __restrict__ dec_w,
                                                   float* __restrict__ ws) {
    __shared__ float gt[18][8];
    __shared__ float Sr[64][8];
    __shared__ float Si[64][8];
    const int t = threadIdx.x;

    if (t < 18) {
        float tx = dec_w[t * 3 + 0];
        float tz = dec_w[t * 3 + 1];
        float c = cosf(0.5f * tx), s = sinf(0.5f * tx);
        float ch = cosf(0.5f * tz), sh = sinf(0.5f * tz);
        gt[t][0] = c * ch;  gt[t][1] = -c * sh;
        gt[t][2] = -s * sh; gt[t][3] = -s * ch;
        gt[t][4] = s * sh;  gt[t][5] = -s * ch;
        gt[t][6] = c * ch;  gt[t][7] = c * sh;
    }

    const int cl = t & 7;
    const int pr = t >> 3;
    float* fSr = &Sr[0][0];
    float* fSi = &Si[0][0];
    for (int f = t; f < 512; f += 256) {
        int r = f >> 3, c = f & 7;
        fSr[f] = (r == c && c < 3) ? 1.0f : 0.0f;
        fSi[f] = 0.0f;
    }

    for (int bb = 0; bb < 3; ++bb) {
        for (int w = 0; w < 6; ++w) {
            __syncthreads();
            int g = bb * 6 + w;
            int p = 5 - w;
            float u00r = gt[g][0], u00i = gt[g][1], u01r = gt[g][2], u01i = gt[g][3];
            float u10r = gt[g][4], u10i = gt[g][5], u11r = gt[g][6], u11i = gt[g][7];
            int r0 = ((pr >> p) << (p + 1)) | (pr & ((1 << p) - 1));
            int r1 = r0 | (1 << p);
            float ar = Sr[r0][cl], ai = Si[r0][cl];
            float br = Sr[r1][cl], bi = Si[r1][cl];
            Sr[r0][cl] = u00r * ar - u00i * ai + u01r * br - u01i * bi;
            Si[r0][cl] = u00r * ai + u00i * ar + u01r * bi + u01i * br;
            Sr[r1][cl] = u10r * ar - u10i * ai + u11r * br - u11i * bi;
            Si[r1][cl] = u10r * ai + u10i * ar + u11r * bi + u11i * br;
        }
        __syncthreads();
        for (int f = t; f < 512; f += 256) {
            int r = f >> 3;
            if (__popc(r & (r >> 1)) & 1) {
                fSr[f] = -fSr[f];
                fSi[f] = -fSi[f];
            }
        }
    }
    __syncthreads();

    // folded decoder quadratic forms: 6 coeffs per output k
    if (t < 36) {
        int k = t / 6, i = t % 6;
        int d = (i < 3) ? i : ((i == 5) ? 1 : 0);  // i=3->(0,1) i=4->(0,2) i=5->(1,2)
        int e = (i < 3) ? i : ((i == 3) ? 1 : 2);
        float acc = 0.0f;
        for (int r = 0; r < 64; ++r) {
            float term = Sr[r][d] * Sr[r][e] + Si[r][d] * Si[r][e];
            acc += ((r >> (5 - k)) & 1) ? -term : term;
        }
        if (i >= 3) acc *= 2.0f;  // symmetric off-diagonal folded
        ws[t] = acc;
    }

    if (t < 18) {
        float tx = enc_w[t * 3 + 0];
        float c = cosf(0.5f * tx), s = sinf(0.5f * tx);
        if (t >= 12) {
            // block 2: observable-folded coefficients
            ws[64 + 2 * t] = c * c - s * s;   // cos(tx)
            ws[65 + 2 * t] = 4.0f * c * s;    // 2*sin(tx)  (Y-exp carries its own 1/2)
        } else {
            ws[64 + 2 * t] = c;
            ws[65 + 2 * t] = s;
        }
    }

    if (t >= 64 && t < 256) {
        int idx = t - 64;
        int bb = idx >> 6, r = idx & 63;
        float phi = 0.0f;
        for (int k = 0; k < 6; ++k) {
            float tz = enc_w[(bb * 6 + k) * 3 + 1];
            phi += ((r >> (5 - k)) & 1) ? 0.5f * tz : -0.5f * tz;
        }
        float sgn = (__popc(r & (r >> 1)) & 1) ? -1.0f : 1.0f;
        ws[128 + bb * 128 + 2 * r] = sgn * cosf(phi);
        ws[129 + bb * 128 + 2 * r] = sgn * sinf(phi);
    }
}

// ---------------------------------------------------------------------------
// Packed butterflies. State: v2f packs P[j] = (amp(m=2j), amp(m=2j+1)),
// amplitude r = 4m + sub, sub = lane&3.
// ---------------------------------------------------------------------------
template <int MASK>  // pack-to-pack RX (wires 0..2: j bits 2,1,0)
__device__ __forceinline__ void rx_pairs(v2f* zr, v2f* zi, float c, float s) {
#pragma unroll
    for (int j = 0; j < 8; ++j) {
        if (j & MASK) continue;
        int j1 = j | MASK;
        v2f ar = zr[j], ai = zi[j], br = zr[j1], bi = zi[j1];
        zr[j]  = c * ar + s * bi;
        zi[j]  = c * ai - s * br;
        zr[j1] = c * br + s * ai;
        zi[j1] = c * bi - s * ar;
    }
}

template <int CTRL>  // cross-lane RX (wires 4,5: lane bits)
__device__ __forceinline__ void rx_exch2(v2f* zr, v2f* zi, float c, float s) {
#pragma unroll
    for (int j = 0; j < 8; ++j) {
        v2f pr, pi;
        pr.x = dppf<CTRL>(zr[j].x);
        pr.y = dppf<CTRL>(zr[j].y);
        pi.x = dppf<CTRL>(zi[j].x);
        pi.y = dppf<CTRL>(zi[j].y);
        v2f mr = zr[j], mi = zi[j];
        zr[j] = c * mr + s * pi;
        zi[j] = c * mi - s * pr;
    }
}

// ---------------------------------------------------------------------------
// main: 4 threads/batch element; 8 v2f packs per thread.
// sW layout: group g = j*4+su holds rows (8j+su, 8j+4+su) interleaved:
//   phys(g,e) = g*16 + (g>>2)*4 + e ; e = 2d+half for W, 12+half bias, 14 pad
// ---------------------------------------------------------------------------
__global__ __launch_bounds__(256) void qae_main(const float* __restrict__ x,
                                                const float* __restrict__ Wp,
                                                const float* __restrict__ bp,
                                                const float* __restrict__ ws,
                                                float* __restrict__ out) {
    __shared__ float sW[540];
    __shared__ float sD[256];   // blocks 0,1: ((bb*8+j)*4+su)*4 = (DrLo,DrHi,DiLo,DiHi)
    __shared__ float sLat[192];

    const int t = threadIdx.x;
    const int bl = t >> 2;
    const int sub = t & 3;

    for (int f = t; f < 512; f += 256) {
        int g = f >> 4, e = f & 15;
        int j = g >> 2, su = g & 3;
        float val;
        if (e < 12)      { int row = 8 * j + su + 4 * (e & 1); val = Wp[row * 6 + (e >> 1)]; }
        else if (e < 14) { int row = 8 * j + su + 4 * (e - 12); val = bp[row]; }
        else val = 0.0f;
        sW[g * 16 + j * 4 + e] = val;
    }
    if (t < 128) {
        int bb = t >> 6, r = t & 63;
        int su = r & 3, m = r >> 2, j = m >> 1, hm = m & 1;
        int base = ((bb * 8 + j) * 4 + su) * 4;
        sD[base + hm]     = ws[128 + bb * 128 + 2 * r];
        sD[base + 2 + hm] = ws[128 + bb * 128 + 2 * r + 1];
    }
    __syncthreads();

    const size_t b = (size_t)blockIdx.x * 64 + bl;
    const float* xp = x + b * 6;
    float2 x01 = *(const float2*)(xp);
    float2 x23 = *(const float2*)(xp + 2);
    float2 x45 = *(const float2*)(xp + 4);
    float xv[6] = {x01.x, x01.y, x23.x, x23.y, x45.x, x45.y};

    // h = tanh(xW^T+b): pack j holds rows (8j+sub, 8j+4+sub)
    v2f zr[8], zi[8];
    v2f S2 = {0.0f, 0.0f};
#pragma unroll
    for (int j = 0; j < 8; ++j) {
        const float* wb = &sW[(j * 4 + sub) * 16 + j * 4];
        float4 c0 = *(const float4*)wb;
        float4 c1 = *(const float4*)(wb + 4);
        float4 c2 = *(const float4*)(wb + 8);
        float4 c3 = *(const float4*)(wb + 12);
        v2f a = {c3.x, c3.y};
        a += xv[0] * (v2f){c0.x, c0.y};
        a += xv[1] * (v2f){c0.z, c0.w};
        a += xv[2] * (v2f){c1.x, c1.y};
        a += xv[3] * (v2f){c1.z, c1.w};
        a += xv[4] * (v2f){c2.x, c2.y};
        a += xv[5] * (v2f){c2.z, c2.w};
        v2f th = {fast_tanh(a.x), fast_tanh(a.y)};
        zr[j] = th;
        zi[j] = (v2f){0.0f, 0.0f};
        S2 += th * th;
    }
    float S = S2.x + S2.y;
    S += dppf<DPP_XOR1>(S);
    S += dppf<DPP_XOR2>(S);
    float invS = __builtin_amdgcn_rcpf(S);

    // encoder circuit, blocks 0 and 1 only (block 2 folded into the observable)
#pragma unroll 1
    for (int bb = 0; bb < 2; ++bb) {
        const float* rx = ws + 64 + 12 * bb;   // uniform -> s_load
        rx_pairs<4>(zr, zi, rx[0], rx[1]);     // wire 0: r bit5 = j bit2
        rx_pairs<2>(zr, zi, rx[2], rx[3]);     // wire 1: r bit4 = j bit1
        rx_pairs<1>(zr, zi, rx[4], rx[5]);     // wire 2: r bit3 = j bit0
        {                                       // wire 3: r bit2 = pack half
            float c = rx[6], s = rx[7];
#pragma unroll
            for (int j = 0; j < 8; ++j) {
                v2f orr = zr[j], oi = zi[j];
                zr[j] = c * orr + s * swap2(oi);
                zi[j] = c * oi - s * swap2(orr);
            }
        }
        rx_exch2<DPP_XOR2>(zr, zi, rx[8], rx[9]);    // wire 4: lane bit1
        rx_exch2<DPP_XOR1>(zr, zi, rx[10], rx[11]);  // wire 5: lane bit0
#pragma unroll
        for (int j = 0; j < 8; ++j) {
            float4 d = *(const float4*)&sD[((bb * 8 + j) * 4 + sub) * 4];
            v2f dr = {d.x, d.y}, di = {d.z, d.w};
            v2f orr = zr[j], oi = zi[j];
            zr[j] = dr * orr - di * oi;
            zi[j] = dr * oi + di * orr;
        }
    }

    // latent via folded block-2 observable:
    //   latent_k = (cos(tx_k)*<Z_k> + sin(tx_k)*<Y_k>)/S
    //   <Z_k> from probs with signs on j bits 2,1,0;
    //   <Y_k> = 2*sum_pairs Im(a0* a1), pairs pack-local (j bits 2,1,0)
    v2f L0 = {0, 0}, L1 = {0, 0}, L2 = {0, 0};
#pragma unroll
    for (int j = 0; j < 8; ++j) {
        v2f p = zr[j] * zr[j] + zi[j] * zi[j];
        L0 += (j & 4) ? -p : p;
        L1 += (j & 2) ? -p : p;
        L2 += (j & 1) ? -p : p;
    }
    v2f Y0 = {0, 0}, Y1 = {0, 0}, Y2 = {0, 0};
#pragma unroll
    for (int j = 0; j < 4; ++j)
        Y0 += zr[j] * zi[j | 4] - zi[j] * zr[j | 4];
#pragma unroll
    for (int j0 = 0; j0 < 8; j0 += 4)
#pragma unroll
        for (int j = j0; j < j0 + 2; ++j)
            Y1 += zr[j] * zi[j | 2] - zi[j] * zr[j | 2];
#pragma unroll
    for (int j = 0; j < 8; j += 2)
        Y2 += zr[j] * zi[j | 1] - zi[j] * zr[j | 1];

    float l0 = L0.x + L0.y, l1 = L1.x + L1.y, l2 = L2.x + L2.y;
    float y0 = Y0.x + Y0.y, y1 = Y1.x + Y1.y, y2 = Y2.x + Y2.y;
    l0 += dppf<DPP_XOR1>(l0); l0 += dppf<DPP_XOR2>(l0);
    l1 += dppf<DPP_XOR1>(l1); l1 += dppf<DPP_XOR2>(l1);
    l2 += dppf<DPP_XOR1>(l2); l2 += dppf<DPP_XOR2>(l2);
    y0 += dppf<DPP_XOR1>(y0); y0 += dppf<DPP_XOR2>(y0);
    y1 += dppf<DPP_XOR1>(y1); y1 += dppf<DPP_XOR2>(y1);
    y2 += dppf<DPP_XOR1>(y2); y2 += dppf<DPP_XOR2>(y2);

    const float* p2 = ws + 88;  // block-2 folded coeffs: (cos tx, 2 sin tx) per wire
    l0 = (p2[0] * l0 + p2[1] * y0) * invS;
    l1 = (p2[2] * l1 + p2[3] * y1) * invS;
    l2 = (p2[4] * l2 + p2[5] * y2) * invS;

    // decoder collapsed + folded: rec_k = (sum_i A'_k[i] q[i]) / (l^T l)
    float q0 = l0 * l0, q1 = l1 * l1, q2 = l2 * l2;
    float q3 = l0 * l1, q4 = l0 * l2, q5 = l1 * l2;
    float r2 = q0 + q1 + q2;
    float invr2 = __builtin_amdgcn_rcpf(r2);
    float rec[6];
#pragma unroll
    for (int k = 0; k < 6; ++k) {
        const float* A = ws + k * 6;  // uniform -> s_load
        float acc = A[0] * q0 + A[1] * q1 + A[2] * q2
                  + A[3] * q3 + A[4] * q4 + A[5] * q5;
        rec[k] = acc * invr2;
    }

    // latent out
    if (sub == 0) {
        sLat[bl * 3 + 0] = l0;
        sLat[bl * 3 + 1] = l1;
        sLat[bl * 3 + 2] = l2;
    }
    __syncthreads();
    if (t < 192) out[(size_t)BATCH * 64 + (size_t)blockIdx.x * 192 + t] = sLat[t];

    // reconstructed = tanh(rec W^T + b); thread covers rows 16*sub..16*sub+15
    const size_t ob = b * 64;
#pragma unroll
    for (int jj = 0; jj < 2; ++jj) {
        int jrow = 2 * sub + jj;
        float vlo[4], vhi[4];
#pragma unroll
        for (int su2 = 0; su2 < 4; ++su2) {
            int g = jrow * 4 + su2;
            const float* wb = &sW[g * 16 + jrow * 4];
            float4 c0 = *(const float4*)wb;
            float4 c1 = *(const float4*)(wb + 4);
            float4 c2 = *(const float4*)(wb + 8);
            float2 b2 = *(const float2*)(wb + 12);
            v2f a = {b2.x, b2.y};
            a += rec[0] * (v2f){c0.x, c0.y};
            a += rec[1] * (v2f){c0.z, c0.w};
            a += rec[2] * (v2f){c1.x, c1.y};
            a += rec[3] * (v2f){c1.z, c1.w};
            a += rec[4] * (v2f){c2.x, c2.y};
            a += rec[5] * (v2f){c2.z, c2.w};
            vlo[su2] = fast_tanh(a.x);   // row 8*jrow + su2
            vhi[su2] = fast_tanh(a.y);   // row 8*jrow + 4 + su2
        }
        float4 o0 = {vlo[0], vlo[1], vlo[2], vlo[3]};
        float4 o1 = {vhi[0], vhi[1], vhi[2], vhi[3]};
        *(float4*)&out[ob + 8 * jrow]     = o0;
        *(float4*)&out[ob + 8 * jrow + 4] = o1;
    }
}

extern "C" void kernel_launch(void* const* d_in, const int* in_sizes, int n_in,
                              void* d_out, int out_size, void* d_ws, size_t ws_size,
                              hipStream_t stream) {
    const float* x   = (const float*)d_in[0];
    const float* Wp  = (const float*)d_in[1];
    const float* bpv = (const float*)d_in[2];
    const float* enc = (const float*)d_in[3];
    const float* dec = (const float*)d_in[4];
    float* out = (float*)d_out;
    float* ws  = (float*)d_ws;

    prep_kernel<<<1, 256, 0, stream>>>(enc, dec, ws);
    qae_main<<<(BATCH * 4) / 256, 256, 0, stream>>>(x, Wp, bpv, ws, out);
}